// Round 6
// baseline (449.514 us; speedup 1.0000x reference)
//
#include <hip/hip_runtime.h>

// Problem constants (from reference config)
#define BATCH 4
#define NCAM  6
#define DNUM  41
#define FHN   8
#define FWN   22
#define CCH   128
#define NXV   200
#define NYV   200
#define NXY   40000      // NXV*NYV
#define NPTS  173184     // BATCH*NCAM*DNUM*FHN*FWN
#define TILE  8          // voxels per tile (power of 2, divides NXY)
#define NTILES (BATCH * NXY / TILE)  // 20000
#define PADC  (CCH + 4)  // LDS row pad
#define CHUNK 128        // points per gather work item
#define WLCAP 32768      // worklist capacity (>= NTILES + NPTS/CHUNK)
#define NBG   2048       // gather grid (8 blocks/CU x 256 CUs, all co-resident)

struct Mats {
    float iR[9];    // inv(post_rots), fp32 LU (gesv-style)
    float comb[9];  // rots @ inv(intrins), fp32 no-FMA matmul
    float tr[3];    // trans
    float pt[3];    // post_trans
};

// fp32 3x3 inverse mimicking numpy's linalg.inv -> LAPACK sgesv (see R1 notes).
__device__ void inv3x3_f32_gesv(const float* __restrict__ Ain, float* __restrict__ inv) {
#pragma clang fp contract(off)
    float A[9];
    for (int k = 0; k < 9; ++k) A[k] = Ain[k];
    int piv[3];
    for (int j = 0; j < 3; ++j) {
        int p = j;
        float amax = fabsf(A[j * 3 + j]);
        for (int i = j + 1; i < 3; ++i) {
            float v = fabsf(A[i * 3 + j]);
            if (v > amax) { amax = v; p = i; }
        }
        piv[j] = p;
        if (p != j)
            for (int k = 0; k < 3; ++k) { float t = A[j*3+k]; A[j*3+k] = A[p*3+k]; A[p*3+k] = t; }
        float rd = 1.0f / A[j * 3 + j];
        for (int i = j + 1; i < 3; ++i) A[i * 3 + j] = A[i * 3 + j] * rd;
        for (int i = j + 1; i < 3; ++i)
            for (int k = j + 1; k < 3; ++k)
                A[i * 3 + k] = A[i * 3 + k] - A[i * 3 + j] * A[j * 3 + k];
    }
    float rdiag[3] = {1.0f / A[0], 1.0f / A[4], 1.0f / A[8]};
    for (int c = 0; c < 3; ++c) {
        float b[3] = {0.0f, 0.0f, 0.0f};
        b[c] = 1.0f;
        for (int j = 0; j < 3; ++j) { int p = piv[j]; if (p != j) { float t = b[j]; b[j] = b[p]; b[p] = t; } }
        for (int k = 0; k < 3; ++k)
            for (int i = k + 1; i < 3; ++i)
                b[i] = b[i] - A[i * 3 + k] * b[k];
        for (int k = 2; k >= 0; --k) {
            b[k] = b[k] * rdiag[k];
            for (int i = 0; i < k; ++i)
                b[i] = b[i] - A[i * 3 + k] * b[k];
        }
        inv[0 + c] = b[0];
        inv[3 + c] = b[1];
        inv[6 + c] = b[2];
    }
}

__global__ void prep_kernel(const float* __restrict__ rots,
                            const float* __restrict__ trans,
                            const float* __restrict__ intrins,
                            const float* __restrict__ post_rots,
                            const float* __restrict__ post_trans,
                            Mats* __restrict__ mats) {
    int i = threadIdx.x;
    if (i >= BATCH * NCAM) return;
    Mats m;
    inv3x3_f32_gesv(post_rots + i * 9, m.iR);
    float invK[9];
    inv3x3_f32_gesv(intrins + i * 9, invK);
    {
#pragma clang fp contract(off)
        for (int r = 0; r < 3; ++r)
            for (int c = 0; c < 3; ++c) {
                float s = rots[i * 9 + r * 3 + 0] * invK[0 * 3 + c];
                s = s + rots[i * 9 + r * 3 + 1] * invK[1 * 3 + c];
                s = s + rots[i * 9 + r * 3 + 2] * invK[2 * 3 + c];
                m.comb[r * 3 + c] = s;
            }
    }
    for (int k = 0; k < 3; ++k) {
        m.tr[k] = trans[i * 3 + k];
        m.pt[k] = post_trans[i * 3 + k];
    }
    mats[i] = m;
}

// Geometry: voxel flat index (b*NXY + gx*NYV + gy) or -1 if dropped.
__device__ __forceinline__ int point_voxel(int p, const Mats* __restrict__ mats) {
#pragma clang fp contract(off)
    int w = p % FWN;
    int t = p / FWN;
    int h = t % FHN;
    t /= FHN;
    int d = t % DNUM;
    t /= DNUM;
    int n = t % NCAM;
    int b = t / NCAM;

    const Mats m = mats[b * NCAM + n];

    float u   = (float)((double)w * (351.0 / 21.0)); // linspace(0,351,22)
    float v   = (float)((double)h * (127.0 / 7.0));  // linspace(0,127,8)
    float dep = 4.0f + (float)d;                     // arange(4,45,1)

    float p0 = u - m.pt[0];
    float p1 = v - m.pt[1];
    float p2 = dep - m.pt[2];
    float q0 = m.iR[0] * p0; q0 = q0 + m.iR[1] * p1; q0 = q0 + m.iR[2] * p2;
    float q1 = m.iR[3] * p0; q1 = q1 + m.iR[4] * p1; q1 = q1 + m.iR[5] * p2;
    float q2 = m.iR[6] * p0; q2 = q2 + m.iR[7] * p1; q2 = q2 + m.iR[8] * p2;
    float r0 = q0 * q2;
    float r1 = q1 * q2;
    float e0 = m.comb[0] * r0; e0 = e0 + m.comb[1] * r1; e0 = e0 + m.comb[2] * q2; e0 = e0 + m.tr[0];
    float e1 = m.comb[3] * r0; e1 = e1 + m.comb[4] * r1; e1 = e1 + m.comb[5] * q2; e1 = e1 + m.tr[1];
    float e2 = m.comb[6] * r0; e2 = e2 + m.comb[7] * r1; e2 = e2 + m.comb[8] * q2; e2 = e2 + m.tr[2];

    float gxf = (e0 + 50.0f) / 0.5f;
    float gyf = (e1 + 50.0f) / 0.5f;
    float gzf = (e2 + 10.0f) / 20.0f;
    int gx = (int)gxf;
    int gy = (int)gyf;
    int gz = (int)gzf;
    if (gx < 0 || gx >= NXV || gy < 0 || gy >= NYV || gz < 0 || gz >= 1) return -1;
    return b * NXY + gx * NYV + gy;
}

// Pass A: per-point vid + per-tile histogram.
__global__ __launch_bounds__(256) void pass_vid_count(const Mats* __restrict__ mats,
                                                      int* __restrict__ vids,
                                                      int* __restrict__ counts) {
    int p = blockIdx.x * 256 + threadIdx.x;
    if (p >= NPTS) return;
    int vid = point_voxel(p, mats);
    vids[p] = vid;
    if (vid >= 0) atomicAdd(&counts[vid >> 3], 1);   // tile = vid/TILE
}

// Exclusive scan of counts -> offsets/cursor, plus chunk-worklist emission.
// One block, 256 threads, 79 tiles/thread (20224 >= 20000).
#define SCAN_PER 79
__global__ __launch_bounds__(256) void scan_kernel(const int* __restrict__ counts,
                                                   int* __restrict__ offsets,
                                                   int* __restrict__ cursor,
                                                   int* __restrict__ wl,
                                                   int* __restrict__ wl_n) {
    __shared__ int csum[256];
    int t = threadIdx.x;
    if (t == 0) *wl_n = 0;   // ws is re-poisoned each launch
    int base = t * SCAN_PER;
    int local[SCAN_PER];
    int s = 0;
    for (int i = 0; i < SCAN_PER; ++i) {
        int idx = base + i;
        int v = (idx < NTILES) ? counts[idx] : 0;
        local[i] = v;
        s += v;
    }
    csum[t] = s;
    __syncthreads();
    for (int off = 1; off < 256; off <<= 1) {
        int v = (t >= off) ? csum[t - off] : 0;
        __syncthreads();
        csum[t] += v;
        __syncthreads();
    }
    int excl = (t > 0) ? csum[t - 1] : 0;
    for (int i = 0; i < SCAN_PER; ++i) {
        int idx = base + i;
        if (idx < NTILES) { offsets[idx] = excl; cursor[idx] = excl; }
        excl += local[i];
    }
    if (t == 255) offsets[NTILES] = excl;
    __syncthreads();   // wl_n zeroed + offsets done before emission
    for (int i = 0; i < SCAN_PER; ++i) {
        int tile = base + i;
        if (tile < NTILES && local[i] > 0) {
            int nch = (local[i] + CHUNK - 1) / CHUNK;
            int pos = atomicAdd(wl_n, nch);
            for (int k = 0; k < nch; ++k)
                wl[pos + k] = (tile << 12) | k;
        }
    }
}

// Pass B: place packed (point, local-voxel) into per-tile segments.
__global__ __launch_bounds__(256) void pass_place(const int* __restrict__ vids,
                                                  int* __restrict__ cursor,
                                                  int2* __restrict__ order2) {
    int p = blockIdx.x * 256 + threadIdx.x;
    if (p >= NPTS) return;
    int vid = vids[p];
    if (vid < 0) return;
    int pos = atomicAdd(&cursor[vid >> 3], 1);
    order2[pos] = make_int2(p, vid & (TILE - 1));
}

// Gather: fixed NBG blocks grid-stride a worklist of <=128-point chunks.
// 8 points in flight (32-lane group per point, float4/lane -> 4 LDS adds).
// Single-chunk tiles store exclusively; multi-chunk (hot) tiles atomicAdd
// onto the memset-zeroed output.
__global__ __launch_bounds__(256) void gather_kernel(const float* __restrict__ feats,
                                                     const int* __restrict__ offsets,
                                                     const int2* __restrict__ order2,
                                                     const int* __restrict__ wl,
                                                     const int* __restrict__ wl_n,
                                                     float* __restrict__ out) {
    __shared__ float acc[TILE][PADC];
    int tid = threadIdx.x;
    int g = tid >> 5;   // point slot 0..7
    int l = tid & 31;   // lane in group: channels 4l..4l+3
    const float4* feats4 = (const float4*)feats;
    int nwl = *wl_n;

    for (int e = blockIdx.x; e < nwl; e += NBG) {
        int entry = wl[e];
        int tile = entry >> 12;
        int k    = entry & 4095;
        int s0 = offsets[tile];
        int s1 = offsets[tile + 1];
        int start = s0 + k * CHUNK;
        int end   = min(s1, start + CHUNK);
        bool multi = (s1 - s0) > CHUNK;

        for (int i = tid; i < TILE * PADC; i += 256)
            ((float*)acc)[i] = 0.0f;
        __syncthreads();

        for (int ip = start + g; ip < end; ip += 8) {
            int2 pv = order2[ip];
            float4 f = feats4[(size_t)pv.x * 32 + l];
            atomicAdd(&acc[pv.y][4 * l + 0], f.x);
            atomicAdd(&acc[pv.y][4 * l + 1], f.y);
            atomicAdd(&acc[pv.y][4 * l + 2], f.z);
            atomicAdd(&acc[pv.y][4 * l + 3], f.w);
        }
        __syncthreads();

        int vbase = tile * TILE;
        int b   = vbase / NXY;
        int xy0 = vbase % NXY;
        int c  = tid >> 1;
        int vq = (tid & 1) * 4;
        float* dst = out + ((size_t)(b * CCH + c)) * NXY + xy0 + vq;
        float4 o;
        o.x = acc[vq + 0][c];
        o.y = acc[vq + 1][c];
        o.z = acc[vq + 2][c];
        o.w = acc[vq + 3][c];
        if (!multi) {
            *(float4*)dst = o;
        } else {
            atomicAdd(dst + 0, o.x);
            atomicAdd(dst + 1, o.y);
            atomicAdd(dst + 2, o.z);
            atomicAdd(dst + 3, o.w);
        }
        __syncthreads();   // flush reads done before next entry zeroes acc
    }
}

// Fallback (round-2 path) if workspace is too small.
__global__ __launch_bounds__(128) void scatter_direct_kernel(const float* __restrict__ feats,
                                                             const Mats* __restrict__ mats,
                                                             float* __restrict__ out) {
    int p = blockIdx.x;
    int vid = point_voxel(p, mats);
    if (vid < 0) return;
    int b  = vid / NXY;
    int xy = vid % NXY;
    int c = threadIdx.x;
    float f = feats[(size_t)p * CCH + c];
    atomicAdd(out + (size_t)(b * CCH + c) * NXY + xy, f);
}

extern "C" void kernel_launch(void* const* d_in, const int* in_sizes, int n_in,
                              void* d_out, int out_size, void* d_ws, size_t ws_size,
                              hipStream_t stream) {
    const float* cam_feats  = (const float*)d_in[0];
    const float* rots       = (const float*)d_in[1];
    const float* trans      = (const float*)d_in[2];
    const float* intrins    = (const float*)d_in[3];
    const float* post_rots  = (const float*)d_in[4];
    const float* post_trans = (const float*)d_in[5];
    float* out = (float*)d_out;

    // Workspace layout (all 8B-aligned)
    const size_t off_mats    = 0;
    const size_t off_vids    = 4096;
    const size_t off_counts  = off_vids    + (size_t)NPTS * 4;         // 20000 ints
    const size_t off_offsets = off_counts  + (size_t)NTILES * 4;       // 20001 ints
    const size_t off_cursor  = off_offsets + (size_t)(NTILES + 2) * 4; // 20000 ints
    const size_t off_wln     = off_cursor  + (size_t)NTILES * 4;       // 1 int (+pad)
    const size_t off_wl      = off_wln     + 8;                        // WLCAP ints
    const size_t off_order2  = off_wl      + (size_t)WLCAP * 4;        // NPTS int2
    const size_t ws_need     = off_order2  + (size_t)NPTS * 8;

    Mats* mats = (Mats*)((char*)d_ws + off_mats);
    prep_kernel<<<1, 64, 0, stream>>>(rots, trans, intrins, post_rots, post_trans, mats);

    if (ws_size >= ws_need) {
        int*  vids    = (int*)((char*)d_ws + off_vids);
        int*  counts  = (int*)((char*)d_ws + off_counts);
        int*  offsets = (int*)((char*)d_ws + off_offsets);
        int*  cursor  = (int*)((char*)d_ws + off_cursor);
        int*  wl_n    = (int*)((char*)d_ws + off_wln);
        int*  wl      = (int*)((char*)d_ws + off_wl);
        int2* order2  = (int2*)((char*)d_ws + off_order2);

        hipMemsetAsync(counts, 0, (size_t)NTILES * 4, stream);
        int pblocks = (NPTS + 255) / 256;
        pass_vid_count<<<pblocks, 256, 0, stream>>>(mats, vids, counts);
        scan_kernel<<<1, 256, 0, stream>>>(counts, offsets, cursor, wl, wl_n);
        pass_place<<<pblocks, 256, 0, stream>>>(vids, cursor, order2);
        hipMemsetAsync(d_out, 0, (size_t)out_size * sizeof(float), stream);
        gather_kernel<<<NBG, 256, 0, stream>>>(cam_feats, offsets, order2, wl, wl_n, out);
    } else {
        hipMemsetAsync(d_out, 0, (size_t)out_size * sizeof(float), stream);
        scatter_direct_kernel<<<NPTS, CCH, 0, stream>>>(cam_feats, mats, out);
    }
}

// Round 8
// 423.605 us; speedup vs baseline: 1.0612x; 1.0612x over previous
//
#include <hip/hip_runtime.h>

// Problem constants (from reference config)
#define BATCH 4
#define NCAM  6
#define DNUM  41
#define FHN   8
#define FWN   22
#define CCH   128
#define NXV   200
#define NYV   200
#define NXY   40000      // NXV*NYV
#define NPTS  173184     // BATCH*NCAM*DNUM*FHN*FWN
#define TILE  32         // voxels per tile: 32 floats = 128B full-line channel runs
#define NTILES (BATCH * NXY / TILE)  // 5000 (40000%32==0, batch-aligned)
#define PADC  (CCH + 1)  // LDS row stride 129: 2-way (free) banks both phases
#define CHUNKB 256       // points handled by base block / per extra entry
#define WLCAP  8192      // extra-entry capacity (worst case ~677)
#define NEXTRA 1024      // extra-kernel grid

struct Mats {
    float iR[9];    // inv(post_rots), fp32 LU (gesv-style)
    float comb[9];  // rots @ inv(intrins), fp32 no-FMA matmul
    float tr[3];    // trans
    float pt[3];    // post_trans
};

// fp32 3x3 inverse mimicking numpy's linalg.inv -> LAPACK sgesv (see R1 notes).
__device__ void inv3x3_f32_gesv(const float* __restrict__ Ain, float* __restrict__ inv) {
#pragma clang fp contract(off)
    float A[9];
    for (int k = 0; k < 9; ++k) A[k] = Ain[k];
    int piv[3];
    for (int j = 0; j < 3; ++j) {
        int p = j;
        float amax = fabsf(A[j * 3 + j]);
        for (int i = j + 1; i < 3; ++i) {
            float v = fabsf(A[i * 3 + j]);
            if (v > amax) { amax = v; p = i; }
        }
        piv[j] = p;
        if (p != j)
            for (int k = 0; k < 3; ++k) { float t = A[j*3+k]; A[j*3+k] = A[p*3+k]; A[p*3+k] = t; }
        float rd = 1.0f / A[j * 3 + j];
        for (int i = j + 1; i < 3; ++i) A[i * 3 + j] = A[i * 3 + j] * rd;
        for (int i = j + 1; i < 3; ++i)
            for (int k = j + 1; k < 3; ++k)
                A[i * 3 + k] = A[i * 3 + k] - A[i * 3 + j] * A[j * 3 + k];
    }
    float rdiag[3] = {1.0f / A[0], 1.0f / A[4], 1.0f / A[8]};
    for (int c = 0; c < 3; ++c) {
        float b[3] = {0.0f, 0.0f, 0.0f};
        b[c] = 1.0f;
        for (int j = 0; j < 3; ++j) { int p = piv[j]; if (p != j) { float t = b[j]; b[j] = b[p]; b[p] = t; } }
        for (int k = 0; k < 3; ++k)
            for (int i = k + 1; i < 3; ++i)
                b[i] = b[i] - A[i * 3 + k] * b[k];
        for (int k = 2; k >= 0; --k) {
            b[k] = b[k] * rdiag[k];
            for (int i = 0; i < k; ++i)
                b[i] = b[i] - A[i * 3 + k] * b[k];
        }
        inv[0 + c] = b[0];
        inv[3 + c] = b[1];
        inv[6 + c] = b[2];
    }
}

__global__ void prep_kernel(const float* __restrict__ rots,
                            const float* __restrict__ trans,
                            const float* __restrict__ intrins,
                            const float* __restrict__ post_rots,
                            const float* __restrict__ post_trans,
                            Mats* __restrict__ mats) {
    int i = threadIdx.x;
    if (i >= BATCH * NCAM) return;
    Mats m;
    inv3x3_f32_gesv(post_rots + i * 9, m.iR);
    float invK[9];
    inv3x3_f32_gesv(intrins + i * 9, invK);
    {
#pragma clang fp contract(off)
        for (int r = 0; r < 3; ++r)
            for (int c = 0; c < 3; ++c) {
                float s = rots[i * 9 + r * 3 + 0] * invK[0 * 3 + c];
                s = s + rots[i * 9 + r * 3 + 1] * invK[1 * 3 + c];
                s = s + rots[i * 9 + r * 3 + 2] * invK[2 * 3 + c];
                m.comb[r * 3 + c] = s;
            }
    }
    for (int k = 0; k < 3; ++k) {
        m.tr[k] = trans[i * 3 + k];
        m.pt[k] = post_trans[i * 3 + k];
    }
    mats[i] = m;
}

// Geometry: voxel flat index (b*NXY + gx*NYV + gy) or -1 if dropped.
__device__ __forceinline__ int point_voxel(int p, const Mats* __restrict__ mats) {
#pragma clang fp contract(off)
    int w = p % FWN;
    int t = p / FWN;
    int h = t % FHN;
    t /= FHN;
    int d = t % DNUM;
    t /= DNUM;
    int n = t % NCAM;
    int b = t / NCAM;

    const Mats m = mats[b * NCAM + n];

    float u   = (float)((double)w * (351.0 / 21.0)); // linspace(0,351,22)
    float v   = (float)((double)h * (127.0 / 7.0));  // linspace(0,127,8)
    float dep = 4.0f + (float)d;                     // arange(4,45,1)

    float p0 = u - m.pt[0];
    float p1 = v - m.pt[1];
    float p2 = dep - m.pt[2];
    float q0 = m.iR[0] * p0; q0 = q0 + m.iR[1] * p1; q0 = q0 + m.iR[2] * p2;
    float q1 = m.iR[3] * p0; q1 = q1 + m.iR[4] * p1; q1 = q1 + m.iR[5] * p2;
    float q2 = m.iR[6] * p0; q2 = q2 + m.iR[7] * p1; q2 = q2 + m.iR[8] * p2;
    float r0 = q0 * q2;
    float r1 = q1 * q2;
    float e0 = m.comb[0] * r0; e0 = e0 + m.comb[1] * r1; e0 = e0 + m.comb[2] * q2; e0 = e0 + m.tr[0];
    float e1 = m.comb[3] * r0; e1 = e1 + m.comb[4] * r1; e1 = e1 + m.comb[5] * q2; e1 = e1 + m.tr[1];
    float e2 = m.comb[6] * r0; e2 = e2 + m.comb[7] * r1; e2 = e2 + m.comb[8] * q2; e2 = e2 + m.tr[2];

    float gxf = (e0 + 50.0f) / 0.5f;
    float gyf = (e1 + 50.0f) / 0.5f;
    float gzf = (e2 + 10.0f) / 20.0f;
    int gx = (int)gxf;
    int gy = (int)gyf;
    int gz = (int)gzf;
    if (gx < 0 || gx >= NXV || gy < 0 || gy >= NYV || gz < 0 || gz >= 1) return -1;
    return b * NXY + gx * NYV + gy;
}

// Pass A: per-point vid + per-tile histogram.
__global__ __launch_bounds__(256) void pass_vid_count(const Mats* __restrict__ mats,
                                                      int* __restrict__ vids,
                                                      int* __restrict__ counts) {
    int p = blockIdx.x * 256 + threadIdx.x;
    if (p >= NPTS) return;
    int vid = point_voxel(p, mats);
    vids[p] = vid;
    if (vid >= 0) atomicAdd(&counts[vid >> 5], 1);   // tile = vid/TILE
}

// Exclusive scan of counts -> offsets/cursor + overflow-chunk worklist.
// One block, 256 threads, 20 tiles/thread (5120 >= 5000).
#define SCAN_PER 20
__global__ __launch_bounds__(256) void scan_kernel(const int* __restrict__ counts,
                                                   int* __restrict__ offsets,
                                                   int* __restrict__ cursor,
                                                   int* __restrict__ wl,
                                                   int* __restrict__ wl_n) {
    __shared__ int csum[256];
    int t = threadIdx.x;
    if (t == 0) *wl_n = 0;   // ws is re-poisoned each launch
    int base = t * SCAN_PER;
    int local[SCAN_PER];
    int s = 0;
    for (int i = 0; i < SCAN_PER; ++i) {
        int idx = base + i;
        int v = (idx < NTILES) ? counts[idx] : 0;
        local[i] = v;
        s += v;
    }
    csum[t] = s;
    __syncthreads();
    for (int off = 1; off < 256; off <<= 1) {
        int v = (t >= off) ? csum[t - off] : 0;
        __syncthreads();
        csum[t] += v;
        __syncthreads();
    }
    int excl = (t > 0) ? csum[t - 1] : 0;
    for (int i = 0; i < SCAN_PER; ++i) {
        int idx = base + i;
        if (idx < NTILES) { offsets[idx] = excl; cursor[idx] = excl; }
        excl += local[i];
    }
    if (t == 255) offsets[NTILES] = excl;
    __syncthreads();   // wl_n zeroed before emission
    for (int i = 0; i < SCAN_PER; ++i) {
        int tile = base + i;
        if (tile < NTILES && local[i] > CHUNKB) {
            int nch = (local[i] + CHUNKB - 1) / CHUNKB;   // >= 2
            int pos = atomicAdd(wl_n, nch - 1);
            for (int k = 1; k < nch; ++k)
                if (pos + k - 1 < WLCAP) wl[pos + k - 1] = (tile << 12) | k;
        }
    }
}

// Pass B: place packed (point, local-voxel) into per-tile segments.
__global__ __launch_bounds__(256) void pass_place(const int* __restrict__ vids,
                                                  int* __restrict__ cursor,
                                                  int2* __restrict__ order2) {
    int p = blockIdx.x * 256 + threadIdx.x;
    if (p >= NPTS) return;
    int vid = vids[p];
    if (vid < 0) return;
    int pos = atomicAdd(&cursor[vid >> 5], 1);
    order2[pos] = make_int2(p, vid & (TILE - 1));
}

// Accumulation helper: 8 point-groups of 32 lanes; lane l owns channels
// l, l+32, l+64, l+96 (stride-32 -> conflict-free ds_add with PADC=129).
__device__ __forceinline__ void accum_points(const float* __restrict__ feats,
                                             const int2* __restrict__ order2,
                                             float* __restrict__ acc,
                                             int start, int end, int g, int l) {
    for (int ip = start + g; ip < end; ip += 8) {
        int2 pv = order2[ip];
        const float* fp = feats + (size_t)pv.x * CCH + l;
        float f0 = fp[0];
        float f1 = fp[32];
        float f2 = fp[64];
        float f3 = fp[96];
        float* row = acc + pv.y * PADC + l;
        atomicAdd(row + 0,  f0);
        atomicAdd(row + 32, f1);
        atomicAdd(row + 64, f2);
        atomicAdd(row + 96, f3);
    }
}

// Base gather: one block per tile, first CHUNKB points, PLAIN stores
// (covers empty tiles with zeros -> no output memset). Full-line writes:
// each channel's 32-float run = 128B contiguous.
// Epilogue: TILE*CCH = 4096 floats = 1024 float4 stores = 4 iters of 256 thr.
__global__ __launch_bounds__(256) void gather_base(const float* __restrict__ feats,
                                                   const int* __restrict__ offsets,
                                                   const int2* __restrict__ order2,
                                                   float* __restrict__ out) {
    __shared__ float acc[TILE * PADC];
    int tile = blockIdx.x;
    int tid = threadIdx.x;
    for (int i = tid; i < TILE * PADC; i += 256) acc[i] = 0.0f;
    __syncthreads();
    int s0 = offsets[tile];
    int s1 = offsets[tile + 1];
    int end = min(s1, s0 + CHUNKB);
    accum_points(feats, order2, acc, s0, end, tid >> 5, tid & 31);
    __syncthreads();
    int vbase = tile * TILE;
    int b   = vbase / NXY;
    int xy0 = vbase % NXY;
#pragma unroll
    for (int i = 0; i < 4; ++i) {               // 4*256 = 1024 float4 stores
        int idx = i * 256 + tid;                // [0,1024)
        int c  = idx >> 3;                      // channel [0,128)
        int vq = (idx & 7) * 4;                 // voxel quad {0..28}
        float4 o;
        o.x = acc[(vq + 0) * PADC + c];
        o.y = acc[(vq + 1) * PADC + c];
        o.z = acc[(vq + 2) * PADC + c];
        o.w = acc[(vq + 3) * PADC + c];
        *(float4*)(out + ((size_t)(b * CCH + c)) * NXY + xy0 + vq) = o;
    }
}

// Extra gather (separate launch AFTER gather_base -> ordering guaranteed):
// grid-strides overflow chunks of hot tiles, atomicAdds onto out.
__global__ __launch_bounds__(256) void gather_extra(const float* __restrict__ feats,
                                                    const int* __restrict__ offsets,
                                                    const int2* __restrict__ order2,
                                                    const int* __restrict__ wl,
                                                    const int* __restrict__ wl_n,
                                                    float* __restrict__ out) {
    __shared__ float acc[TILE * PADC];
    int tid = threadIdx.x;
    int nwl = *wl_n;
    for (int e = blockIdx.x; e < nwl && e < WLCAP; e += NEXTRA) {
        int entry = wl[e];
        int tile = entry >> 12;
        int k    = entry & 4095;
        int s0 = offsets[tile];
        int s1 = offsets[tile + 1];
        int start = s0 + k * CHUNKB;
        int end   = min(s1, start + CHUNKB);
        for (int i = tid; i < TILE * PADC; i += 256) acc[i] = 0.0f;
        __syncthreads();
        accum_points(feats, order2, acc, start, end, tid >> 5, tid & 31);
        __syncthreads();
        int vbase = tile * TILE;
        int b   = vbase / NXY;
        int xy0 = vbase % NXY;
        for (int i = 0; i < 4; ++i) {           // 1024 float4-sized adds
            int idx = i * 256 + tid;
            int c  = idx >> 3;
            int vq = (idx & 7) * 4;
            float* dst = out + ((size_t)(b * CCH + c)) * NXY + xy0 + vq;
            atomicAdd(dst + 0, acc[(vq + 0) * PADC + c]);
            atomicAdd(dst + 1, acc[(vq + 1) * PADC + c]);
            atomicAdd(dst + 2, acc[(vq + 2) * PADC + c]);
            atomicAdd(dst + 3, acc[(vq + 3) * PADC + c]);
        }
        __syncthreads();   // all reads of acc done before next iteration zeroes
    }
}

// Fallback (round-2 path) if workspace is too small.
__global__ __launch_bounds__(128) void scatter_direct_kernel(const float* __restrict__ feats,
                                                             const Mats* __restrict__ mats,
                                                             float* __restrict__ out) {
    int p = blockIdx.x;
    int vid = point_voxel(p, mats);
    if (vid < 0) return;
    int b  = vid / NXY;
    int xy = vid % NXY;
    int c = threadIdx.x;
    float f = feats[(size_t)p * CCH + c];
    atomicAdd(out + (size_t)(b * CCH + c) * NXY + xy, f);
}

extern "C" void kernel_launch(void* const* d_in, const int* in_sizes, int n_in,
                              void* d_out, int out_size, void* d_ws, size_t ws_size,
                              hipStream_t stream) {
    const float* cam_feats  = (const float*)d_in[0];
    const float* rots       = (const float*)d_in[1];
    const float* trans      = (const float*)d_in[2];
    const float* intrins    = (const float*)d_in[3];
    const float* post_rots  = (const float*)d_in[4];
    const float* post_trans = (const float*)d_in[5];
    float* out = (float*)d_out;

    // Workspace layout (all 8B-aligned)
    const size_t off_mats    = 0;
    const size_t off_vids    = 4096;
    const size_t off_counts  = off_vids    + (size_t)NPTS * 4;
    const size_t off_offsets = off_counts  + (size_t)NTILES * 4;
    const size_t off_cursor  = off_offsets + (size_t)(NTILES + 2) * 4;
    const size_t off_wln     = off_cursor  + (size_t)NTILES * 4;
    const size_t off_wl      = off_wln     + 8;
    const size_t off_order2  = off_wl      + (size_t)WLCAP * 4;
    const size_t ws_need     = off_order2  + (size_t)NPTS * 8;

    Mats* mats = (Mats*)((char*)d_ws + off_mats);
    prep_kernel<<<1, 64, 0, stream>>>(rots, trans, intrins, post_rots, post_trans, mats);

    if (ws_size >= ws_need) {
        int*  vids    = (int*)((char*)d_ws + off_vids);
        int*  counts  = (int*)((char*)d_ws + off_counts);
        int*  offsets = (int*)((char*)d_ws + off_offsets);
        int*  cursor  = (int*)((char*)d_ws + off_cursor);
        int*  wl_n    = (int*)((char*)d_ws + off_wln);
        int*  wl      = (int*)((char*)d_ws + off_wl);
        int2* order2  = (int2*)((char*)d_ws + off_order2);

        hipMemsetAsync(counts, 0, (size_t)NTILES * 4, stream);
        int pblocks = (NPTS + 255) / 256;
        pass_vid_count<<<pblocks, 256, 0, stream>>>(mats, vids, counts);
        scan_kernel<<<1, 256, 0, stream>>>(counts, offsets, cursor, wl, wl_n);
        pass_place<<<pblocks, 256, 0, stream>>>(vids, cursor, order2);
        gather_base<<<NTILES, 256, 0, stream>>>(cam_feats, offsets, order2, out);
        gather_extra<<<NEXTRA, 256, 0, stream>>>(cam_feats, offsets, order2, wl, wl_n, out);
    } else {
        hipMemsetAsync(d_out, 0, (size_t)out_size * sizeof(float), stream);
        scatter_direct_kernel<<<NPTS, CCH, 0, stream>>>(cam_feats, mats, out);
    }
}